// Round 7
// baseline (267.075 us; speedup 1.0000x reference)
//
#include <hip/hip_runtime.h>
#include <math.h>

// Problem constants
constexpr int SEQ   = 512;
constexpr int HDIM  = 64;
constexpr int NHEAD = 12;
constexpr int NBATCH = 2;
constexpr int CDIM  = 768;
constexpr int TOPM  = 16;
constexpr int SMAX  = 8;
constexpr float NEGINF = -1e30f;

// ---------------------------------------------------------------
// Kernel 1: QKV = x @ w_qkv + b_qkv, scattered to q/k/v [24,512,64]
// 64x64 tile, BK=32, DOUBLE-BUFFERED LDS: chunk t+1's global loads
// are issued before computing chunk t (latency hides under FMAs).
// K-summation order identical to prior rounds -> bitwise-identical
// q/k/v (keeps all discrete DPP selections unchanged).
// ---------------------------------------------------------------
__global__ __launch_bounds__(256) void qkv_gemm_kernel(
    const float* __restrict__ x, const float* __restrict__ w,
    const float* __restrict__ bias,
    float* __restrict__ q, float* __restrict__ k, float* __restrict__ v)
{
    __shared__ float As[2][32][68];
    __shared__ float Bs[2][32][68];
    const int bm = blockIdx.y * 64;
    const int bn = blockIdx.x * 64;
    const int tid = threadIdx.x;
    const int tm = (tid >> 4) << 2;
    const int tn = (tid & 15) << 2;
    const int alm = tid >> 2;
    const int alk = (tid & 3) << 3;
    const int blk = tid >> 3;
    const int bln = (tid & 7) << 3;
    const int NCH = CDIM / 32;          // 24 chunks

    float acc[4][4] = {};
    // prologue: stage chunk 0
    {
        float4 a0 = *(const float4*)(x + (bm + alm) * CDIM + alk);
        float4 a1 = *(const float4*)(x + (bm + alm) * CDIM + alk + 4);
        float4 b0 = *(const float4*)(w + blk * (3 * CDIM) + bn + bln);
        float4 b1 = *(const float4*)(w + blk * (3 * CDIM) + bn + bln + 4);
        As[0][alk + 0][alm] = a0.x; As[0][alk + 1][alm] = a0.y;
        As[0][alk + 2][alm] = a0.z; As[0][alk + 3][alm] = a0.w;
        As[0][alk + 4][alm] = a1.x; As[0][alk + 5][alm] = a1.y;
        As[0][alk + 6][alm] = a1.z; As[0][alk + 7][alm] = a1.w;
        *(float4*)&Bs[0][blk][bln] = b0;
        *(float4*)&Bs[0][blk][bln + 4] = b1;
    }
    __syncthreads();

    for (int t = 0; t < NCH; ++t) {
        const int cur = t & 1;
        float4 na0, na1, nb0, nb1;
        if (t + 1 < NCH) {
            int k0 = (t + 1) * 32;
            na0 = *(const float4*)(x + (bm + alm) * CDIM + k0 + alk);
            na1 = *(const float4*)(x + (bm + alm) * CDIM + k0 + alk + 4);
            nb0 = *(const float4*)(w + (k0 + blk) * (3 * CDIM) + bn + bln);
            nb1 = *(const float4*)(w + (k0 + blk) * (3 * CDIM) + bn + bln + 4);
        }
        #pragma unroll
        for (int kk = 0; kk < 32; ++kk) {
            float4 a4 = *(const float4*)&As[cur][kk][tm];
            float4 b4 = *(const float4*)&Bs[cur][kk][tn];
            float a[4] = {a4.x, a4.y, a4.z, a4.w};
            float b[4] = {b4.x, b4.y, b4.z, b4.w};
            #pragma unroll
            for (int u = 0; u < 4; ++u)
                #pragma unroll
                for (int w2 = 0; w2 < 4; ++w2)
                    acc[u][w2] = fmaf(a[u], b[w2], acc[u][w2]);
        }
        __syncthreads();
        if (t + 1 < NCH) {
            const int nxt = cur ^ 1;
            As[nxt][alk + 0][alm] = na0.x; As[nxt][alk + 1][alm] = na0.y;
            As[nxt][alk + 2][alm] = na0.z; As[nxt][alk + 3][alm] = na0.w;
            As[nxt][alk + 4][alm] = na1.x; As[nxt][alk + 5][alm] = na1.y;
            As[nxt][alk + 6][alm] = na1.z; As[nxt][alk + 7][alm] = na1.w;
            *(float4*)&Bs[nxt][blk][bln] = nb0;
            *(float4*)&Bs[nxt][blk][bln + 4] = nb1;
            __syncthreads();
        }
    }
    #pragma unroll
    for (int u = 0; u < 4; ++u) {
        int m = bm + tm + u;
        int b_ = m >> 9, t = m & 511;
        #pragma unroll
        for (int w2 = 0; w2 < 4; ++w2) {
            int cc = bn + tn + w2;
            float val = acc[u][w2] + bias[cc];
            int part = cc / CDIM;
            int c2 = cc - part * CDIM;
            int h = c2 >> 6, d = c2 & 63;
            float* dst = (part == 0) ? q : ((part == 1) ? k : v);
            dst[(((b_ * NHEAD + h) * SEQ) + t) * HDIM + d] = val;
        }
    }
}

// ---------------------------------------------------------------
// Kernel 2: fused S = QK^T and KKT (lower-tri 64x64 tiles).
// S fp32 (order unchanged -> identical bits). KKT now fp32-accum:
// same error class as the reference's own fp32 Gram (~1e-6 rel);
// R3->R4 precision shifts of this size never moved a selection.
// ---------------------------------------------------------------
__global__ __launch_bounds__(256) void qkkt_kernel(
    const float* __restrict__ q, const float* __restrict__ k,
    float* __restrict__ S, float* __restrict__ KKT)
{
    __shared__ float Qs[64][68];   // [d][token_i]
    __shared__ float Ka[64][68];   // [d][token_i] keys (row tile)
    __shared__ float Kb[64][68];   // [d][token_j] keys (col tile)
    const int e = blockIdx.x;      // 0..35 lower-tri tile
    const int n = blockIdx.y;
    int it = 0, start = 0;
    while (start + it + 1 <= e) { start += it + 1; ++it; }
    const int jt = e - start;
    const int tid = threadIdx.x;
    const float* qh = q + (size_t)n * SEQ * HDIM;
    const float* kh = k + (size_t)n * SEQ * HDIM;

    #pragma unroll
    for (int l = 0; l < 4; ++l) {
        int idx = tid + l * 256;             // 0..1023
        int tok = idx >> 4, q4 = (idx & 15) << 2;
        float4 qv = *(const float4*)(qh + (it * 64 + tok) * HDIM + q4);
        Qs[q4 + 0][tok] = qv.x; Qs[q4 + 1][tok] = qv.y;
        Qs[q4 + 2][tok] = qv.z; Qs[q4 + 3][tok] = qv.w;
        float4 ka = *(const float4*)(kh + (it * 64 + tok) * HDIM + q4);
        Ka[q4 + 0][tok] = ka.x; Ka[q4 + 1][tok] = ka.y;
        Ka[q4 + 2][tok] = ka.z; Ka[q4 + 3][tok] = ka.w;
        float4 kb = *(const float4*)(kh + (jt * 64 + tok) * HDIM + q4);
        Kb[q4 + 0][tok] = kb.x; Kb[q4 + 1][tok] = kb.y;
        Kb[q4 + 2][tok] = kb.z; Kb[q4 + 3][tok] = kb.w;
    }
    __syncthreads();

    const int tm = (tid >> 4) << 2;
    const int tn = (tid & 15) << 2;
    float sacc[4][4] = {};
    float gacc[4][4] = {};
    #pragma unroll 8
    for (int d = 0; d < 64; ++d) {
        float4 q4 = *(const float4*)&Qs[d][tm];
        float4 a4 = *(const float4*)&Ka[d][tm];
        float4 b4 = *(const float4*)&Kb[d][tn];
        float qa[4] = {q4.x, q4.y, q4.z, q4.w};
        float aa[4] = {a4.x, a4.y, a4.z, a4.w};
        float bb[4] = {b4.x, b4.y, b4.z, b4.w};
        #pragma unroll
        for (int u = 0; u < 4; ++u)
            #pragma unroll
            for (int w2 = 0; w2 < 4; ++w2) {
                sacc[u][w2] = fmaf(qa[u], bb[w2], sacc[u][w2]);
                gacc[u][w2] = fmaf(aa[u], bb[w2], gacc[u][w2]);
            }
    }
    float* gdst = KKT + ((size_t)n * 36 + e) * 4096;
    #pragma unroll
    for (int u = 0; u < 4; ++u) {
        int i = it * 64 + tm + u;
        float4 o = {sacc[u][0], sacc[u][1], sacc[u][2], sacc[u][3]};
        *(float4*)(S + ((size_t)n * SEQ + i) * SEQ + jt * 64 + tn) = o;
        float4 g = {gacc[u][0], gacc[u][1], gacc[u][2], gacc[u][3]};
        *(float4*)(gdst + (tm + u) * 64 + tn) = g;
    }
}

// hybrid log: exact exponent + hardware f32 log2 of mantissa.
// abs err ~1e-7 << ref's fp32-det/fp32-log noise (~4e-6).
__device__ inline double hybrid_log(double a)
{
    a = fmax(a, 1e-300);
    unsigned long long b = __double_as_longlong(a);
    int e2 = (int)((b >> 52) & 0x7FF) - 1022;
    double m = __longlong_as_double((b & 0x000FFFFFFFFFFFFFULL) |
                                    0x3FE0000000000000ULL);   // [0.5,1)
    return ((double)__log2f((float)m) + (double)e2) * 0.6931471805599453;
}

// ---------------------------------------------------------------
// Kernel 3: per-token DPP. One wave per token, 4 tokens per block.
// ---------------------------------------------------------------
__global__ __launch_bounds__(256) void dpp_kernel(
    const float* __restrict__ v, float* __restrict__ S,
    const float* __restrict__ KKT, const float* __restrict__ gate_p,
    float* __restrict__ y, float* __restrict__ denomArr)
{
    const int tid  = threadIdx.x;
    const int wid  = tid >> 6;
    const int lane = tid & 63;
    const int i = blockIdx.x * 4 + wid;
    const int n = blockIdx.y;
    const float* vh = v + (size_t)n * SEQ * HDIM;
    const float* KKTh = KKT + (size_t)n * 36 * 4096;
    float* Srow = S + ((size_t)n * SEQ + i) * SEQ;

    __shared__ float  prow[4][SEQ];
    __shared__ double gram[4][17][17];
    __shared__ int    eidx[4][17];

    // ---- load sim row (masked) ----
    float sim8[8];
    #pragma unroll
    for (int m = 0; m < 8; ++m) {
        int j = lane + (m << 6);
        sim8[m] = (j <= i) ? Srow[j] : NEGINF;
    }

    // ---- top-16 via packed sortable-u64 key (stable ties = lowest idx) ----
    {
        float vals[8];
        #pragma unroll
        for (int m = 0; m < 8; ++m) vals[m] = sim8[m];
        if (lane == 0) eidx[wid][0] = i;
        #pragma unroll
        for (int s = 0; s < TOPM; ++s) {
            float bv = vals[0]; int bi = lane;
            #pragma unroll
            for (int m = 1; m < 8; ++m)
                if (vals[m] > bv) { bv = vals[m]; bi = lane + (m << 6); }
            unsigned u = __float_as_uint(bv);
            u ^= (u & 0x80000000u) ? 0xFFFFFFFFu : 0x80000000u;
            unsigned long long key =
                ((unsigned long long)u << 9) | (unsigned)(511 - bi);
            #pragma unroll
            for (int off = 32; off; off >>= 1) {
                unsigned long long ok = __shfl_xor(key, off);
                if (ok > key) key = ok;
            }
            int ri = 511 - (int)(key & 511ull);
            if (lane == 0) eidx[wid][1 + s] = ri;
            if ((ri & 63) == lane) {
                int om = ri >> 6;
                #pragma unroll
                for (int m = 0; m < 8; ++m) if (m == om) vals[m] = -2e30f;
            }
        }
    }

    // ---- softmax stats; write numerators to LDS + global (P over S) ----
    const float scale = 0.125f;
    float lm = -3e38f;
    #pragma unroll
    for (int m = 0; m < 8; ++m) lm = fmaxf(lm, sim8[m]);
    #pragma unroll
    for (int off = 32; off; off >>= 1) lm = fmaxf(lm, __shfl_xor(lm, off));
    const float mx = lm * scale;
    float sum = 0.f;
    #pragma unroll
    for (int m = 0; m < 8; ++m) {
        float p = expf(sim8[m] * scale - mx);   // 0 for masked entries
        int j = lane + (m << 6);
        prow[wid][j] = p;
        Srow[j] = p;
        sum += p;
    }
    #pragma unroll
    for (int off = 32; off; off >>= 1) sum += __shfl_xor(sum, off);
    const float denom = sum;
    __syncthreads();

    // ---- 17x17 Gram: gather from precomputed KKT ----
    for (int e = lane; e < 153; e += 64) {
        int a = 0, st = 0;
        while (st + a + 1 <= e) { st += a + 1; ++a; }
        int b = e - st;
        int ra = eidx[wid][a], rb = eidx[wid][b];
        int row = ra > rb ? ra : rb;
        int col = ra > rb ? rb : ra;
        int itt = row >> 6, jtt = col >> 6;
        int p = ((itt * (itt + 1)) >> 1) + jtt;
        double s = (double)KKTh[((size_t)p * 64 + (row & 63)) * 64 + (col & 63)];
        gram[wid][a][b] = s;
        gram[wid][b][a] = s;
    }
    __syncthreads();

    // ---- greedy DPP via incremental Cholesky ----
    int selI[SMAX];
    int sc = 1;
    {
        const int c = lane;
        const bool isCand = (c < TOPM);
        const int nvalid = (i + 1 < TOPM) ? (i + 1) : TOPM;
        bool active = isCand && (c < nvalid) && (eidx[wid][1 + c] != i);
        double zc[7];
        #pragma unroll
        for (int t = 0; t < 7; ++t) zc[t] = 0.0;
        double det = gram[wid][0][0];
        double cur = hybrid_log(det + 1e-6);
        double L00 = sqrt(det > 0.0 ? det : 1e-30);
        double dcv = 0.0;
        if (isCand) {
            zc[0] = gram[wid][1 + c][0] / L00;
            dcv = gram[wid][1 + c][1 + c] - zc[0] * zc[0];
        }
        #pragma unroll
        for (int t = 0; t < SMAX; ++t) selI[t] = i;

        for (int it = 0; it < SMAX - 1; ++it) {
            double argc = det * dcv + 1e-6;
            // candidate ranking key (monotone in score; arg<=0 == NaN wins)
            double key = active ? (argc > 0.0 ? argc : 1e300) : -1.0;
            int rc = c;
            #pragma unroll
            for (int off = 1; off <= 8; off <<= 1) {   // reduce among 16 cands
                double ov = __shfl_xor(key, off);
                int    oc = __shfl_xor(rc, off);
                if (ov > key || (ov == key && oc < rc)) { key = ov; rc = oc; }
            }
            rc = __shfl(rc, 0);                        // broadcast winner
            bool any = (__any(active ? 1 : 0) != 0);
            double dbest = __shfl(dcv, rc);
            double argb = det * dbest + 1e-6;
            bool   pos  = argb > 0.0;
            double score = hybrid_log(pos ? argb : 1.0) / (double)(sc + 1);
            bool take = any && ((pos && score > cur) || (sc < 4));
            if (!take) break;

            double Lss = sqrt(dbest > 1e-30 ? dbest : 1e-30);
            double zb[7];
            #pragma unroll
            for (int t = 0; t < 7; ++t) zb[t] = __shfl(zc[t], rc);
            if (isCand) {
                double crossn = gram[wid][1 + c][1 + rc];
                double s2 = 0.0;
                #pragma unroll
                for (int t = 0; t < 7; ++t) if (t < sc) s2 += zc[t] * zb[t];
                double znew = (crossn - s2) / Lss;
                #pragma unroll
                for (int t = 0; t < 7; ++t) if (t == sc) zc[t] = znew;
                dcv -= znew * znew;
            }
            det = det * dbest;
            cur = pos ? score : __builtin_nan("");     // NaN: future cmp false
            if (c == rc) active = false;
            int newIdx = eidx[wid][1 + rc];
            #pragma unroll
            for (int t = 0; t < SMAX; ++t) if (t == sc) selI[t] = newIdx;
            ++sc;
        }
    }

    // ---- gated DPP part -> y (pv_gemm accumulates the std part) ----
    float wsum = 0.f;
    #pragma unroll
    for (int s = 0; s < SMAX; ++s) if (s < sc) wsum += prow[wid][selI[s]];
    float yd = 0.f;
    #pragma unroll
    for (int s = 0; s < SMAX; ++s)
        if (s < sc) yd = fmaf(prow[wid][selI[s]], vh[selI[s] * HDIM + lane], yd);
    const float gp = gate_p[0];
    const float gate = 1.f / (1.f + expf(-gp));
    y[((size_t)n * SEQ + i) * HDIM + lane] = gate * yd / wsum;
    if (lane == 0) denomArr[n * SEQ + i] = denom;
}

// ---------------------------------------------------------------
// Kernel 4: y += (1-gate) * (P @ V)/denom  (causal j-chunk skip)
// ---------------------------------------------------------------
__global__ __launch_bounds__(256) void pv_gemm_kernel(
    const float* __restrict__ P, const float* __restrict__ v,
    const float* __restrict__ denomArr, const float* __restrict__ gate_p,
    float* __restrict__ y)
{
    __shared__ float Ps[32][68];   // [j][token]
    __shared__ float Vs[32][68];   // [j][d]
    const int tt = blockIdx.x;
    const int n  = blockIdx.y;
    const int t0 = tt * 64;
    const int tid = threadIdx.x;
    const float* Ph = P + (size_t)n * SEQ * SEQ;
    const float* vh = v + (size_t)n * SEQ * HDIM;
    const int tm = (tid >> 4) << 2;
    const int tn = (tid & 15) << 2;
    float acc[4][4] = {};
    const int jmax = t0 + 64;
    for (int j0 = 0; j0 < jmax; j0 += 32) {
        #pragma unroll
        for (int l = 0; l < 2; ++l) {
            int idx = tid + l * 256;
            int tok = idx >> 3, j4 = (idx & 7) << 2;
            float4 p4 = *(const float4*)(Ph + (t0 + tok) * SEQ + j0 + j4);
            Ps[j4 + 0][tok] = p4.x; Ps[j4 + 1][tok] = p4.y;
            Ps[j4 + 2][tok] = p4.z; Ps[j4 + 3][tok] = p4.w;
        }
        #pragma unroll
        for (int l = 0; l < 2; ++l) {
            int idx = tid + l * 256;
            int j = idx >> 4, d4 = (idx & 15) << 2;
            *(float4*)&Vs[j][d4] = *(const float4*)(vh + (j0 + j) * HDIM + d4);
        }
        __syncthreads();
        #pragma unroll
        for (int j = 0; j < 32; ++j) {
            float4 a4 = *(const float4*)&Ps[j][tm];
            float4 b4 = *(const float4*)&Vs[j][tn];
            float a[4] = {a4.x, a4.y, a4.z, a4.w};
            float b[4] = {b4.x, b4.y, b4.z, b4.w};
            #pragma unroll
            for (int u = 0; u < 4; ++u)
                #pragma unroll
                for (int w2 = 0; w2 < 4; ++w2)
                    acc[u][w2] = fmaf(a[u], b[w2], acc[u][w2]);
        }
        __syncthreads();
    }
    const float gp = gate_p[0];
    const float gate = 1.f / (1.f + expf(-gp));
    #pragma unroll
    for (int u = 0; u < 4; ++u) {
        int i = t0 + tm + u;
        float den = denomArr[n * SEQ + i];
        #pragma unroll
        for (int w2 = 0; w2 < 4; ++w2) {
            int d = tn + w2;
            size_t off = ((size_t)n * SEQ + i) * HDIM + d;
            y[off] += (1.f - gate) * acc[u][w2] / den;
        }
    }
}

// ---------------------------------------------------------------
// Kernel 5: out = reshape(y) @ w_proj + b_proj (gathered A), BK=32,
// double-buffered like kernel 1.
// ---------------------------------------------------------------
__global__ __launch_bounds__(256) void proj_gemm_kernel(
    const float* __restrict__ y, const float* __restrict__ w,
    const float* __restrict__ bias, float* __restrict__ out)
{
    __shared__ float As[2][32][68];
    __shared__ float Bs[2][32][68];
    const int bm = blockIdx.y * 64;
    const int bn = blockIdx.x * 64;
    const int tid = threadIdx.x;
    const int tm = (tid >> 4) << 2;
    const int tn = (tid & 15) << 2;
    const int alm = tid >> 2;
    const int alk = (tid & 3) << 3;
    const int blk = tid >> 3;
    const int bln = (tid & 7) << 3;
    const int NCH = CDIM / 32;
    const int row = bm + alm;
    const int b_ = row >> 9, tk = row & 511;
    const float* ybase = y + (((size_t)b_ * NHEAD) * SEQ + tk) * HDIM;

    float acc[4][4] = {};
    {
        int h0 = alk >> 6, d0 = alk & 63;          // alk<64 so h0=0
        float4 a0 = *(const float4*)(ybase + (size_t)h0 * SEQ * HDIM + d0);
        int col1 = alk + 4;
        int h1 = col1 >> 6, d1 = col1 & 63;
        float4 a1 = *(const float4*)(ybase + (size_t)h1 * SEQ * HDIM + d1);
        float4 b0 = *(const float4*)(w + blk * CDIM + bn + bln);
        float4 b1 = *(const float4*)(w + blk * CDIM + bn + bln + 4);
        As[0][alk + 0][alm] = a0.x; As[0][alk + 1][alm] = a0.y;
        As[0][alk + 2][alm] = a0.z; As[0][alk + 3][alm] = a0.w;
        As[0][alk + 4][alm] = a1.x; As[0][alk + 5][alm] = a1.y;
        As[0][alk + 6][alm] = a1.z; As[0][alk + 7][alm] = a1.w;
        *(float4*)&Bs[0][blk][bln] = b0;
        *(float4*)&Bs[0][blk][bln + 4] = b1;
    }
    __syncthreads();

    for (int t = 0; t < NCH; ++t) {
        const int cur = t & 1;
        float4 na0, na1, nb0, nb1;
        if (t + 1 < NCH) {
            int k0 = (t + 1) * 32;
            int col0 = k0 + alk;
            int h0 = col0 >> 6, d0 = col0 & 63;
            na0 = *(const float4*)(ybase + (size_t)h0 * SEQ * HDIM + d0);
            int col1 = col0 + 4;
            int h1 = col1 >> 6, d1 = col1 & 63;
            na1 = *(const float4*)(ybase + (size_t)h1 * SEQ * HDIM + d1);
            nb0 = *(const float4*)(w + (k0 + blk) * CDIM + bn + bln);
            nb1 = *(const float4*)(w + (k0 + blk) * CDIM + bn + bln + 4);
        }
        #pragma unroll
        for (int kk = 0; kk < 32; ++kk) {
            float4 a4 = *(const float4*)&As[cur][kk][tm];
            float4 b4 = *(const float4*)&Bs[cur][kk][tn];
            float a[4] = {a4.x, a4.y, a4.z, a4.w};
            float b[4] = {b4.x, b4.y, b4.z, b4.w};
            #pragma unroll
            for (int u = 0; u < 4; ++u)
                #pragma unroll
                for (int w2 = 0; w2 < 4; ++w2)
                    acc[u][w2] = fmaf(a[u], b[w2], acc[u][w2]);
        }
        __syncthreads();
        if (t + 1 < NCH) {
            const int nxt = cur ^ 1;
            As[nxt][alk + 0][alm] = na0.x; As[nxt][alk + 1][alm] = na0.y;
            As[nxt][alk + 2][alm] = na0.z; As[nxt][alk + 3][alm] = na0.w;
            As[nxt][alk + 4][alm] = na1.x; As[nxt][alk + 5][alm] = na1.y;
            As[nxt][alk + 6][alm] = na1.z; As[nxt][alk + 7][alm] = na1.w;
            *(float4*)&Bs[nxt][blk][bln] = nb0;
            *(float4*)&Bs[nxt][blk][bln + 4] = nb1;
            __syncthreads();
        }
    }
    #pragma unroll
    for (int u = 0; u < 4; ++u) {
        int m = bm + tm + u;
        #pragma unroll
        for (int w2 = 0; w2 < 4; ++w2) {
            int cc = bn + tn + w2;
            out[m * CDIM + cc] = acc[u][w2] + bias[cc];
        }
    }
}

extern "C" void kernel_launch(void* const* d_in, const int* in_sizes, int n_in,
                              void* d_out, int out_size, void* d_ws, size_t ws_size,
                              hipStream_t stream)
{
    const float* x      = (const float*)d_in[0];
    const float* w_qkv  = (const float*)d_in[1];
    const float* b_qkv  = (const float*)d_in[2];
    const float* w_proj = (const float*)d_in[3];
    const float* b_proj = (const float*)d_in[4];
    const float* gate_p = (const float*)d_in[5];
    float* out = (float*)d_out;

    float* ws = (float*)d_ws;
    const size_t HS = (size_t)NBATCH * NHEAD * SEQ * HDIM;   // 786432
    const size_t SS = (size_t)NBATCH * NHEAD * SEQ * SEQ;    // 6291456
    float* q   = ws;
    float* k   = q + HS;
    float* v   = k + HS;
    float* y   = v + HS;
    float* S   = y + HS;                 // sim, becomes P in-place
    float* den = S + SS;
    float* KKT = den + 16384;            // 24*36*4096 floats, packed tiles

    qkv_gemm_kernel<<<dim3((3 * CDIM) / 64, (NBATCH * SEQ) / 64), 256, 0, stream>>>(
        x, w_qkv, b_qkv, q, k, v);
    qkkt_kernel<<<dim3(36, NBATCH * NHEAD), 256, 0, stream>>>(q, k, S, KKT);
    dpp_kernel<<<dim3(SEQ / 4, NBATCH * NHEAD), 256, 0, stream>>>(
        v, S, KKT, gate_p, y, den);
    pv_gemm_kernel<<<dim3(SEQ / 64, NBATCH * NHEAD), 256, 0, stream>>>(
        S, v, den, gate_p, y);
    proj_gemm_kernel<<<dim3(CDIM / 64, (NBATCH * SEQ) / 64), 256, 0, stream>>>(
        y, w_proj, b_proj, out);
}

// Round 8
// 205.403 us; speedup vs baseline: 1.3002x; 1.3002x over previous
//
#include <hip/hip_runtime.h>
#include <math.h>

// Problem constants
constexpr int SEQ   = 512;
constexpr int HDIM  = 64;
constexpr int NHEAD = 12;
constexpr int NBATCH = 2;
constexpr int CDIM  = 768;
constexpr int TOPM  = 16;
constexpr int SMAX  = 8;
constexpr float NEGINF = -1e30f;

// ---------------------------------------------------------------
// Kernel 1a: QKV partial GEMM, K-split x2. Each block: 64x64 tile,
// K range [bz*384, bz*384+384), BK=32, single-buffered (R6 dbuf
// regressed occupancy). A staged [m][k] with float4 writes ->
// conflict-free; reads per-4-k float4 keep ascending-k FMA chain.
// ---------------------------------------------------------------
__global__ __launch_bounds__(256) void qkv_gemm_kernel(
    const float* __restrict__ x, const float* __restrict__ w,
    float* __restrict__ partial)
{
    __shared__ float As[64][36];
    __shared__ float Bs[32][68];
    const int bm = blockIdx.y * 64;
    const int bn = blockIdx.x * 64;
    const int kbase = blockIdx.z * 384;
    const int tid = threadIdx.x;
    const int tm = (tid >> 4) << 2;
    const int tn = (tid & 15) << 2;
    const int alm = tid >> 2;
    const int alk = (tid & 3) << 3;
    const int blk = tid >> 3;
    const int bln = (tid & 7) << 3;
    float acc[4][4] = {};
    for (int t = 0; t < 12; ++t) {
        const int k0 = kbase + t * 32;
        float4 a0 = *(const float4*)(x + (bm + alm) * CDIM + k0 + alk);
        float4 a1 = *(const float4*)(x + (bm + alm) * CDIM + k0 + alk + 4);
        float4 b0 = *(const float4*)(w + (k0 + blk) * (3 * CDIM) + bn + bln);
        float4 b1 = *(const float4*)(w + (k0 + blk) * (3 * CDIM) + bn + bln + 4);
        *(float4*)&As[alm][alk] = a0;
        *(float4*)&As[alm][alk + 4] = a1;
        *(float4*)&Bs[blk][bln] = b0;
        *(float4*)&Bs[blk][bln + 4] = b1;
        __syncthreads();
        #pragma unroll
        for (int k4 = 0; k4 < 8; ++k4) {
            float4 a0r = *(const float4*)&As[tm + 0][k4 << 2];
            float4 a1r = *(const float4*)&As[tm + 1][k4 << 2];
            float4 a2r = *(const float4*)&As[tm + 2][k4 << 2];
            float4 a3r = *(const float4*)&As[tm + 3][k4 << 2];
            float ar[4][4] = {{a0r.x, a0r.y, a0r.z, a0r.w},
                              {a1r.x, a1r.y, a1r.z, a1r.w},
                              {a2r.x, a2r.y, a2r.z, a2r.w},
                              {a3r.x, a3r.y, a3r.z, a3r.w}};
            #pragma unroll
            for (int j = 0; j < 4; ++j) {
                float4 b4 = *(const float4*)&Bs[(k4 << 2) + j][tn];
                float bb[4] = {b4.x, b4.y, b4.z, b4.w};
                #pragma unroll
                for (int u = 0; u < 4; ++u)
                    #pragma unroll
                    for (int w2 = 0; w2 < 4; ++w2)
                        acc[u][w2] = fmaf(ar[u][j], bb[w2], acc[u][w2]);
            }
        }
        __syncthreads();
    }
    float* dst = partial + (size_t)blockIdx.z * (1024 * 2304);
    #pragma unroll
    for (int u = 0; u < 4; ++u) {
        float4 o = {acc[u][0], acc[u][1], acc[u][2], acc[u][3]};
        *(float4*)(dst + (size_t)(bm + tm + u) * 2304 + bn + tn) = o;
    }
}

// ---------------------------------------------------------------
// Kernel 1b: qkv reduce: (p0+p1)+bias, scatter to q/k/v layout.
// ---------------------------------------------------------------
__global__ __launch_bounds__(256) void qkv_reduce_kernel(
    const float* __restrict__ partial, const float* __restrict__ bias,
    float* __restrict__ q, float* __restrict__ k, float* __restrict__ v)
{
    const int idx = blockIdx.x * 256 + threadIdx.x;   // 0..589823
    const int m = idx / 576;
    const int cc = (idx - m * 576) << 2;
    float4 p0 = *(const float4*)(partial + (size_t)m * 2304 + cc);
    float4 p1 = *(const float4*)(partial + (size_t)1024 * 2304 + (size_t)m * 2304 + cc);
    float4 b4 = *(const float4*)(bias + cc);
    float4 o = {p0.x + p1.x + b4.x, p0.y + p1.y + b4.y,
                p0.z + p1.z + b4.z, p0.w + p1.w + b4.w};
    const int part = cc / CDIM;
    const int c2 = cc - part * CDIM;
    const int h = c2 >> 6, d = c2 & 63;
    const int b_ = m >> 9, t = m & 511;
    float* dst = (part == 0) ? q : ((part == 1) ? k : v);
    *(float4*)(dst + ((((size_t)b_ * NHEAD + h) * SEQ) + t) * HDIM + d) = o;
}

// ---------------------------------------------------------------
// Kernel 2: fused S = QK^T and KKT (lower-tri 64x64 tiles).
// LDS now [token][d] (direct float4 staging, no transpose-write
// conflicts); chained x/y/z/w FMAs keep ascending-d order ->
// bitwise-identical S and KKT vs prior rounds.
// ---------------------------------------------------------------
__global__ __launch_bounds__(256) void qkkt_kernel(
    const float* __restrict__ q, const float* __restrict__ k,
    float* __restrict__ S, float* __restrict__ KKT)
{
    __shared__ float Qs[64][68];   // [token_i][d]
    __shared__ float Ka[64][68];   // [token_i][d] keys (row tile)
    __shared__ float Kb[64][68];   // [token_j][d] keys (col tile)
    const int e = blockIdx.x;      // 0..35 lower-tri tile
    const int n = blockIdx.y;
    int it = 0, start = 0;
    while (start + it + 1 <= e) { start += it + 1; ++it; }
    const int jt = e - start;
    const int tid = threadIdx.x;
    const float* qh = q + (size_t)n * SEQ * HDIM;
    const float* kh = k + (size_t)n * SEQ * HDIM;

    #pragma unroll
    for (int l = 0; l < 4; ++l) {
        int idx = tid + l * 256;             // 0..1023
        int tok = idx >> 4, d4 = (idx & 15) << 2;
        *(float4*)&Qs[tok][d4] = *(const float4*)(qh + (it * 64 + tok) * HDIM + d4);
        *(float4*)&Ka[tok][d4] = *(const float4*)(kh + (it * 64 + tok) * HDIM + d4);
        *(float4*)&Kb[tok][d4] = *(const float4*)(kh + (jt * 64 + tok) * HDIM + d4);
    }
    __syncthreads();

    const int tm = (tid >> 4) << 2;
    const int tn = (tid & 15) << 2;
    float sacc[4][4] = {};
    float gacc[4][4] = {};
    #pragma unroll 4
    for (int d4 = 0; d4 < 16; ++d4) {
        float4 qr[4], ar[4], br[4];
        #pragma unroll
        for (int u = 0; u < 4; ++u) {
            qr[u] = *(const float4*)&Qs[tm + u][d4 << 2];
            ar[u] = *(const float4*)&Ka[tm + u][d4 << 2];
        }
        #pragma unroll
        for (int w2 = 0; w2 < 4; ++w2)
            br[w2] = *(const float4*)&Kb[tn + w2][d4 << 2];
        #pragma unroll
        for (int u = 0; u < 4; ++u)
            #pragma unroll
            for (int w2 = 0; w2 < 4; ++w2) {
                float s = sacc[u][w2];
                s = fmaf(qr[u].x, br[w2].x, s);
                s = fmaf(qr[u].y, br[w2].y, s);
                s = fmaf(qr[u].z, br[w2].z, s);
                s = fmaf(qr[u].w, br[w2].w, s);
                sacc[u][w2] = s;
                float g = gacc[u][w2];
                g = fmaf(ar[u].x, br[w2].x, g);
                g = fmaf(ar[u].y, br[w2].y, g);
                g = fmaf(ar[u].z, br[w2].z, g);
                g = fmaf(ar[u].w, br[w2].w, g);
                gacc[u][w2] = g;
            }
    }
    float* gdst = KKT + ((size_t)n * 36 + e) * 4096;
    #pragma unroll
    for (int u = 0; u < 4; ++u) {
        int i = it * 64 + tm + u;
        float4 o = {sacc[u][0], sacc[u][1], sacc[u][2], sacc[u][3]};
        *(float4*)(S + ((size_t)n * SEQ + i) * SEQ + jt * 64 + tn) = o;
        float4 g = {gacc[u][0], gacc[u][1], gacc[u][2], gacc[u][3]};
        *(float4*)(gdst + (tm + u) * 64 + tn) = g;
    }
}

// hybrid log: exact exponent + hardware f32 log2 of mantissa.
// abs err ~1e-7 << ref's fp32-det/fp32-log noise (~4e-6).
__device__ inline double hybrid_log(double a)
{
    a = fmax(a, 1e-300);
    unsigned long long b = __double_as_longlong(a);
    int e2 = (int)((b >> 52) & 0x7FF) - 1022;
    double m = __longlong_as_double((b & 0x000FFFFFFFFFFFFFULL) |
                                    0x3FE0000000000000ULL);   // [0.5,1)
    return ((double)__log2f((float)m) + (double)e2) * 0.6931471805599453;
}

// ---------------------------------------------------------------
// Kernel 3: per-token DPP. One wave per token, 4 tokens per block.
// ---------------------------------------------------------------
__global__ __launch_bounds__(256) void dpp_kernel(
    const float* __restrict__ v, float* __restrict__ S,
    const float* __restrict__ KKT, const float* __restrict__ gate_p,
    float* __restrict__ y, float* __restrict__ denomArr)
{
    const int tid  = threadIdx.x;
    const int wid  = tid >> 6;
    const int lane = tid & 63;
    const int i = blockIdx.x * 4 + wid;
    const int n = blockIdx.y;
    const float* vh = v + (size_t)n * SEQ * HDIM;
    const float* KKTh = KKT + (size_t)n * 36 * 4096;
    float* Srow = S + ((size_t)n * SEQ + i) * SEQ;

    __shared__ float  prow[4][SEQ];
    __shared__ double gram[4][17][17];
    __shared__ int    eidx[4][17];

    // ---- load sim row (masked) ----
    float sim8[8];
    #pragma unroll
    for (int m = 0; m < 8; ++m) {
        int j = lane + (m << 6);
        sim8[m] = (j <= i) ? Srow[j] : NEGINF;
    }

    // ---- top-16 via packed sortable-u64 key (stable ties = lowest idx) ----
    {
        float vals[8];
        #pragma unroll
        for (int m = 0; m < 8; ++m) vals[m] = sim8[m];
        if (lane == 0) eidx[wid][0] = i;
        #pragma unroll
        for (int s = 0; s < TOPM; ++s) {
            float bv = vals[0]; int bi = lane;
            #pragma unroll
            for (int m = 1; m < 8; ++m)
                if (vals[m] > bv) { bv = vals[m]; bi = lane + (m << 6); }
            unsigned u = __float_as_uint(bv);
            u ^= (u & 0x80000000u) ? 0xFFFFFFFFu : 0x80000000u;
            unsigned long long key =
                ((unsigned long long)u << 9) | (unsigned)(511 - bi);
            #pragma unroll
            for (int off = 32; off; off >>= 1) {
                unsigned long long ok = __shfl_xor(key, off);
                if (ok > key) key = ok;
            }
            int ri = 511 - (int)(key & 511ull);
            if (lane == 0) eidx[wid][1 + s] = ri;
            if ((ri & 63) == lane) {
                int om = ri >> 6;
                #pragma unroll
                for (int m = 0; m < 8; ++m) if (m == om) vals[m] = -2e30f;
            }
        }
    }

    // ---- softmax stats; write numerators to LDS + global (P over S) ----
    const float scale = 0.125f;
    float lm = -3e38f;
    #pragma unroll
    for (int m = 0; m < 8; ++m) lm = fmaxf(lm, sim8[m]);
    #pragma unroll
    for (int off = 32; off; off >>= 1) lm = fmaxf(lm, __shfl_xor(lm, off));
    const float mx = lm * scale;
    float sum = 0.f;
    #pragma unroll
    for (int m = 0; m < 8; ++m) {
        float p = expf(sim8[m] * scale - mx);   // 0 for masked entries
        int j = lane + (m << 6);
        prow[wid][j] = p;
        Srow[j] = p;
        sum += p;
    }
    #pragma unroll
    for (int off = 32; off; off >>= 1) sum += __shfl_xor(sum, off);
    const float denom = sum;
    __syncthreads();

    // ---- 17x17 Gram: gather from precomputed KKT ----
    for (int e = lane; e < 153; e += 64) {
        int a = 0, st = 0;
        while (st + a + 1 <= e) { st += a + 1; ++a; }
        int b = e - st;
        int ra = eidx[wid][a], rb = eidx[wid][b];
        int row = ra > rb ? ra : rb;
        int col = ra > rb ? rb : ra;
        int itt = row >> 6, jtt = col >> 6;
        int p = ((itt * (itt + 1)) >> 1) + jtt;
        double s = (double)KKTh[((size_t)p * 64 + (row & 63)) * 64 + (col & 63)];
        gram[wid][a][b] = s;
        gram[wid][b][a] = s;
    }
    __syncthreads();

    // ---- greedy DPP via incremental Cholesky ----
    int selI[SMAX];
    int sc = 1;
    {
        const int c = lane;
        const bool isCand = (c < TOPM);
        const int nvalid = (i + 1 < TOPM) ? (i + 1) : TOPM;
        bool active = isCand && (c < nvalid) && (eidx[wid][1 + c] != i);
        double zc[7];
        #pragma unroll
        for (int t = 0; t < 7; ++t) zc[t] = 0.0;
        double det = gram[wid][0][0];
        double cur = hybrid_log(det + 1e-6);
        double L00 = sqrt(det > 0.0 ? det : 1e-30);
        double dcv = 0.0;
        if (isCand) {
            zc[0] = gram[wid][1 + c][0] / L00;
            dcv = gram[wid][1 + c][1 + c] - zc[0] * zc[0];
        }
        #pragma unroll
        for (int t = 0; t < SMAX; ++t) selI[t] = i;

        for (int it = 0; it < SMAX - 1; ++it) {
            double argc = det * dcv + 1e-6;
            // candidate ranking key (monotone in score; arg<=0 == NaN wins)
            double key = active ? (argc > 0.0 ? argc : 1e300) : -1.0;
            int rc = c;
            #pragma unroll
            for (int off = 1; off <= 8; off <<= 1) {   // reduce among 16 cands
                double ov = __shfl_xor(key, off);
                int    oc = __shfl_xor(rc, off);
                if (ov > key || (ov == key && oc < rc)) { key = ov; rc = oc; }
            }
            rc = __shfl(rc, 0);                        // broadcast winner
            bool any = (__any(active ? 1 : 0) != 0);
            double dbest = __shfl(dcv, rc);
            double argb = det * dbest + 1e-6;
            bool   pos  = argb > 0.0;
            double score = hybrid_log(pos ? argb : 1.0) / (double)(sc + 1);
            bool take = any && ((pos && score > cur) || (sc < 4));
            if (!take) break;

            double Lss = sqrt(dbest > 1e-30 ? dbest : 1e-30);
            double zb[7];
            #pragma unroll
            for (int t = 0; t < 7; ++t) zb[t] = __shfl(zc[t], rc);
            if (isCand) {
                double crossn = gram[wid][1 + c][1 + rc];
                double s2 = 0.0;
                #pragma unroll
                for (int t = 0; t < 7; ++t) if (t < sc) s2 += zc[t] * zb[t];
                double znew = (crossn - s2) / Lss;
                #pragma unroll
                for (int t = 0; t < 7; ++t) if (t == sc) zc[t] = znew;
                dcv -= znew * znew;
            }
            det = det * dbest;
            cur = pos ? score : __builtin_nan("");     // NaN: future cmp false
            if (c == rc) active = false;
            int newIdx = eidx[wid][1 + rc];
            #pragma unroll
            for (int t = 0; t < SMAX; ++t) if (t == sc) selI[t] = newIdx;
            ++sc;
        }
    }

    // ---- gated DPP part -> y (pv_gemm accumulates the std part) ----
    float wsum = 0.f;
    #pragma unroll
    for (int s = 0; s < SMAX; ++s) if (s < sc) wsum += prow[wid][selI[s]];
    float yd = 0.f;
    #pragma unroll
    for (int s = 0; s < SMAX; ++s)
        if (s < sc) yd = fmaf(prow[wid][selI[s]], vh[selI[s] * HDIM + lane], yd);
    const float gp = gate_p[0];
    const float gate = 1.f / (1.f + expf(-gp));
    y[((size_t)n * SEQ + i) * HDIM + lane] = gate * yd / wsum;
    if (lane == 0) denomArr[n * SEQ + i] = denom;
}

// ---------------------------------------------------------------
// Kernel 4: y += (1-gate) * (P @ V)/denom  (causal j-chunk skip).
// P staged [token][j] (direct float4 writes, conflict-free);
// ascending-j chain order preserved -> bitwise-identical.
// ---------------------------------------------------------------
__global__ __launch_bounds__(256) void pv_gemm_kernel(
    const float* __restrict__ P, const float* __restrict__ v,
    const float* __restrict__ denomArr, const float* __restrict__ gate_p,
    float* __restrict__ y)
{
    __shared__ float Ps[64][36];   // [token][j]
    __shared__ float Vs[32][68];   // [j][d]
    const int tt = blockIdx.x;
    const int n  = blockIdx.y;
    const int t0 = tt * 64;
    const int tid = threadIdx.x;
    const float* Ph = P + (size_t)n * SEQ * SEQ;
    const float* vh = v + (size_t)n * SEQ * HDIM;
    const int tm = (tid >> 4) << 2;
    const int tn = (tid & 15) << 2;
    float acc[4][4] = {};
    const int jmax = t0 + 64;
    for (int j0 = 0; j0 < jmax; j0 += 32) {
        #pragma unroll
        for (int l = 0; l < 2; ++l) {
            int idx = tid + l * 256;          // 0..511
            int tok = idx >> 3, j4 = (idx & 7) << 2;
            *(float4*)&Ps[tok][j4] =
                *(const float4*)(Ph + (t0 + tok) * SEQ + j0 + j4);
        }
        #pragma unroll
        for (int l = 0; l < 2; ++l) {
            int idx = tid + l * 256;
            int j = idx >> 4, d4 = (idx & 15) << 2;
            *(float4*)&Vs[j][d4] = *(const float4*)(vh + (j0 + j) * HDIM + d4);
        }
        __syncthreads();
        #pragma unroll
        for (int j4 = 0; j4 < 8; ++j4) {
            float4 p0r = *(const float4*)&Ps[tm + 0][j4 << 2];
            float4 p1r = *(const float4*)&Ps[tm + 1][j4 << 2];
            float4 p2r = *(const float4*)&Ps[tm + 2][j4 << 2];
            float4 p3r = *(const float4*)&Ps[tm + 3][j4 << 2];
            float pr[4][4] = {{p0r.x, p0r.y, p0r.z, p0r.w},
                              {p1r.x, p1r.y, p1r.z, p1r.w},
                              {p2r.x, p2r.y, p2r.z, p2r.w},
                              {p3r.x, p3r.y, p3r.z, p3r.w}};
            #pragma unroll
            for (int l = 0; l < 4; ++l) {
                float4 v4 = *(const float4*)&Vs[(j4 << 2) + l][tn];
                float vv[4] = {v4.x, v4.y, v4.z, v4.w};
                #pragma unroll
                for (int u = 0; u < 4; ++u)
                    #pragma unroll
                    for (int w2 = 0; w2 < 4; ++w2)
                        acc[u][w2] = fmaf(pr[u][l], vv[w2], acc[u][w2]);
            }
        }
        __syncthreads();
    }
    const float gp = gate_p[0];
    const float gate = 1.f / (1.f + expf(-gp));
    #pragma unroll
    for (int u = 0; u < 4; ++u) {
        int i = t0 + tm + u;
        float den = denomArr[n * SEQ + i];
        #pragma unroll
        for (int w2 = 0; w2 < 4; ++w2) {
            int d = tn + w2;
            size_t off = ((size_t)n * SEQ + i) * HDIM + d;
            y[off] += (1.f - gate) * acc[u][w2] / den;
        }
    }
}

// ---------------------------------------------------------------
// Kernel 5a: proj partial GEMM, K-split x4 (gathered A), BK=32.
// ---------------------------------------------------------------
__global__ __launch_bounds__(256) void proj_gemm_kernel(
    const float* __restrict__ y, const float* __restrict__ w,
    float* __restrict__ partial)
{
    __shared__ float As[64][36];
    __shared__ float Bs[32][68];
    const int bm = blockIdx.y * 64;
    const int bn = blockIdx.x * 64;
    const int kbase = blockIdx.z * 192;
    const int tid = threadIdx.x;
    const int tm = (tid >> 4) << 2;
    const int tn = (tid & 15) << 2;
    const int alm = tid >> 2;
    const int alk = (tid & 3) << 3;
    const int blk = tid >> 3;
    const int bln = (tid & 7) << 3;
    const int row = bm + alm;
    const int b_ = row >> 9, tk = row & 511;
    const float* ybase = y + (((size_t)b_ * NHEAD) * SEQ + tk) * HDIM;

    float acc[4][4] = {};
    for (int t = 0; t < 6; ++t) {
        const int k0 = kbase + t * 32;
        int col0 = k0 + alk;
        int h0 = col0 >> 6, d0 = col0 & 63;
        float4 a0 = *(const float4*)(ybase + (size_t)h0 * SEQ * HDIM + d0);
        int col1 = col0 + 4;
        int h1 = col1 >> 6, d1 = col1 & 63;
        float4 a1 = *(const float4*)(ybase + (size_t)h1 * SEQ * HDIM + d1);
        float4 b0 = *(const float4*)(w + (k0 + blk) * CDIM + bn + bln);
        float4 b1 = *(const float4*)(w + (k0 + blk) * CDIM + bn + bln + 4);
        *(float4*)&As[alm][alk] = a0;
        *(float4*)&As[alm][alk + 4] = a1;
        *(float4*)&Bs[blk][bln] = b0;
        *(float4*)&Bs[blk][bln + 4] = b1;
        __syncthreads();
        #pragma unroll
        for (int k4 = 0; k4 < 8; ++k4) {
            float4 a0r = *(const float4*)&As[tm + 0][k4 << 2];
            float4 a1r = *(const float4*)&As[tm + 1][k4 << 2];
            float4 a2r = *(const float4*)&As[tm + 2][k4 << 2];
            float4 a3r = *(const float4*)&As[tm + 3][k4 << 2];
            float ar[4][4] = {{a0r.x, a0r.y, a0r.z, a0r.w},
                              {a1r.x, a1r.y, a1r.z, a1r.w},
                              {a2r.x, a2r.y, a2r.z, a2r.w},
                              {a3r.x, a3r.y, a3r.z, a3r.w}};
            #pragma unroll
            for (int j = 0; j < 4; ++j) {
                float4 b4 = *(const float4*)&Bs[(k4 << 2) + j][tn];
                float bb[4] = {b4.x, b4.y, b4.z, b4.w};
                #pragma unroll
                for (int u = 0; u < 4; ++u)
                    #pragma unroll
                    for (int w2 = 0; w2 < 4; ++w2)
                        acc[u][w2] = fmaf(ar[u][j], bb[w2], acc[u][w2]);
            }
        }
        __syncthreads();
    }
    float* dst = partial + (size_t)blockIdx.z * (1024 * 768);
    #pragma unroll
    for (int u = 0; u < 4; ++u) {
        float4 o = {acc[u][0], acc[u][1], acc[u][2], acc[u][3]};
        *(float4*)(dst + (size_t)(bm + tm + u) * 768 + bn + tn) = o;
    }
}

// ---------------------------------------------------------------
// Kernel 5b: proj reduce: p0+p1+p2+p3+bias -> out.
// ---------------------------------------------------------------
__global__ __launch_bounds__(256) void proj_reduce_kernel(
    const float* __restrict__ partial, const float* __restrict__ bias,
    float* __restrict__ out)
{
    const int idx = blockIdx.x * 256 + threadIdx.x;   // 0..196607
    const int m = idx / 192;
    const int cc = (idx - m * 192) << 2;
    const size_t MN = (size_t)1024 * 768;
    float4 p0 = *(const float4*)(partial + (size_t)m * 768 + cc);
    float4 p1 = *(const float4*)(partial + MN + (size_t)m * 768 + cc);
    float4 p2 = *(const float4*)(partial + 2 * MN + (size_t)m * 768 + cc);
    float4 p3 = *(const float4*)(partial + 3 * MN + (size_t)m * 768 + cc);
    float4 b4 = *(const float4*)(bias + cc);
    float4 o = {((p0.x + p1.x) + p2.x) + p3.x + b4.x,
                ((p0.y + p1.y) + p2.y) + p3.y + b4.y,
                ((p0.z + p1.z) + p2.z) + p3.z + b4.z,
                ((p0.w + p1.w) + p2.w) + p3.w + b4.w};
    *(float4*)(out + (size_t)m * 768 + cc) = o;
}

extern "C" void kernel_launch(void* const* d_in, const int* in_sizes, int n_in,
                              void* d_out, int out_size, void* d_ws, size_t ws_size,
                              hipStream_t stream)
{
    const float* x      = (const float*)d_in[0];
    const float* w_qkv  = (const float*)d_in[1];
    const float* b_qkv  = (const float*)d_in[2];
    const float* w_proj = (const float*)d_in[3];
    const float* b_proj = (const float*)d_in[4];
    const float* gate_p = (const float*)d_in[5];
    float* out = (float*)d_out;

    float* ws = (float*)d_ws;
    const size_t HS = (size_t)NBATCH * NHEAD * SEQ * HDIM;   // 786432
    const size_t SS = (size_t)NBATCH * NHEAD * SEQ * SEQ;    // 6291456
    float* q   = ws;
    float* k   = q + HS;
    float* v   = k + HS;
    float* y   = v + HS;
    float* S   = y + HS;                 // sim->P in place; also reused
                                         // as GEMM partial scratch
    float* den = S + SS;
    float* KKT = den + 16384;            // 24*36*4096 floats, packed tiles

    // qkv partials (2*1024*2304 = 4.7M floats) live in the S region,
    // which is free until qkkt writes it.
    qkv_gemm_kernel<<<dim3((3 * CDIM) / 64, (NBATCH * SEQ) / 64, 2), 256, 0, stream>>>(
        x, w_qkv, S);
    qkv_reduce_kernel<<<2304, 256, 0, stream>>>(S, b_qkv, q, k, v);
    qkkt_kernel<<<dim3(36, NBATCH * NHEAD), 256, 0, stream>>>(q, k, S, KKT);
    dpp_kernel<<<dim3(SEQ / 4, NBATCH * NHEAD), 256, 0, stream>>>(
        v, S, KKT, gate_p, y, den);
    pv_gemm_kernel<<<dim3(SEQ / 64, NBATCH * NHEAD), 256, 0, stream>>>(
        S, v, den, gate_p, y);
    // proj partials (4*1024*768 = 3.1M floats) reuse S (free after pv).
    proj_gemm_kernel<<<dim3(CDIM / 64, (NBATCH * SEQ) / 64, 4), 256, 0, stream>>>(
        y, w_proj, S);
    proj_reduce_kernel<<<768, 256, 0, stream>>>(S, b_proj, out);
}

// Round 9
// 193.305 us; speedup vs baseline: 1.3816x; 1.0626x over previous
//
#include <hip/hip_runtime.h>
#include <math.h>

// Problem constants
constexpr int SEQ   = 512;
constexpr int HDIM  = 64;
constexpr int NHEAD = 12;
constexpr int NBATCH = 2;
constexpr int CDIM  = 768;
constexpr int TOPM  = 16;
constexpr int SMAX  = 8;
constexpr float NEGINF = -1e30f;

// ---------------------------------------------------------------
// Kernel 1a: QKV partial GEMM, K-split x2 (unchanged from R7).
// ---------------------------------------------------------------
__global__ __launch_bounds__(256) void qkv_gemm_kernel(
    const float* __restrict__ x, const float* __restrict__ w,
    float* __restrict__ partial)
{
    __shared__ float As[64][36];
    __shared__ float Bs[32][68];
    const int bm = blockIdx.y * 64;
    const int bn = blockIdx.x * 64;
    const int kbase = blockIdx.z * 384;
    const int tid = threadIdx.x;
    const int tm = (tid >> 4) << 2;
    const int tn = (tid & 15) << 2;
    const int alm = tid >> 2;
    const int alk = (tid & 3) << 3;
    const int blk = tid >> 3;
    const int bln = (tid & 7) << 3;
    float acc[4][4] = {};
    for (int t = 0; t < 12; ++t) {
        const int k0 = kbase + t * 32;
        float4 a0 = *(const float4*)(x + (bm + alm) * CDIM + k0 + alk);
        float4 a1 = *(const float4*)(x + (bm + alm) * CDIM + k0 + alk + 4);
        float4 b0 = *(const float4*)(w + (k0 + blk) * (3 * CDIM) + bn + bln);
        float4 b1 = *(const float4*)(w + (k0 + blk) * (3 * CDIM) + bn + bln + 4);
        *(float4*)&As[alm][alk] = a0;
        *(float4*)&As[alm][alk + 4] = a1;
        *(float4*)&Bs[blk][bln] = b0;
        *(float4*)&Bs[blk][bln + 4] = b1;
        __syncthreads();
        #pragma unroll
        for (int k4 = 0; k4 < 8; ++k4) {
            float4 a0r = *(const float4*)&As[tm + 0][k4 << 2];
            float4 a1r = *(const float4*)&As[tm + 1][k4 << 2];
            float4 a2r = *(const float4*)&As[tm + 2][k4 << 2];
            float4 a3r = *(const float4*)&As[tm + 3][k4 << 2];
            float ar[4][4] = {{a0r.x, a0r.y, a0r.z, a0r.w},
                              {a1r.x, a1r.y, a1r.z, a1r.w},
                              {a2r.x, a2r.y, a2r.z, a2r.w},
                              {a3r.x, a3r.y, a3r.z, a3r.w}};
            #pragma unroll
            for (int j = 0; j < 4; ++j) {
                float4 b4 = *(const float4*)&Bs[(k4 << 2) + j][tn];
                float bb[4] = {b4.x, b4.y, b4.z, b4.w};
                #pragma unroll
                for (int u = 0; u < 4; ++u)
                    #pragma unroll
                    for (int w2 = 0; w2 < 4; ++w2)
                        acc[u][w2] = fmaf(ar[u][j], bb[w2], acc[u][w2]);
            }
        }
        __syncthreads();
    }
    float* dst = partial + (size_t)blockIdx.z * (1024 * 2304);
    #pragma unroll
    for (int u = 0; u < 4; ++u) {
        float4 o = {acc[u][0], acc[u][1], acc[u][2], acc[u][3]};
        *(float4*)(dst + (size_t)(bm + tm + u) * 2304 + bn + tn) = o;
    }
}

// ---------------------------------------------------------------
// Kernel 1b: qkv reduce (unchanged).
// ---------------------------------------------------------------
__global__ __launch_bounds__(256) void qkv_reduce_kernel(
    const float* __restrict__ partial, const float* __restrict__ bias,
    float* __restrict__ q, float* __restrict__ k, float* __restrict__ v)
{
    const int idx = blockIdx.x * 256 + threadIdx.x;   // 0..589823
    const int m = idx / 576;
    const int cc = (idx - m * 576) << 2;
    float4 p0 = *(const float4*)(partial + (size_t)m * 2304 + cc);
    float4 p1 = *(const float4*)(partial + (size_t)1024 * 2304 + (size_t)m * 2304 + cc);
    float4 b4 = *(const float4*)(bias + cc);
    float4 o = {p0.x + p1.x + b4.x, p0.y + p1.y + b4.y,
                p0.z + p1.z + b4.z, p0.w + p1.w + b4.w};
    const int part = cc / CDIM;
    const int c2 = cc - part * CDIM;
    const int h = c2 >> 6, d = c2 & 63;
    const int b_ = m >> 9, t = m & 511;
    float* dst = (part == 0) ? q : ((part == 1) ? k : v);
    *(float4*)(dst + ((((size_t)b_ * NHEAD + h) * SEQ) + t) * HDIM + d) = o;
}

// ---------------------------------------------------------------
// Kernel 2: fused S = QK^T and KKT (unchanged from R7).
// ---------------------------------------------------------------
__global__ __launch_bounds__(256) void qkkt_kernel(
    const float* __restrict__ q, const float* __restrict__ k,
    float* __restrict__ S, float* __restrict__ KKT)
{
    __shared__ float Qs[64][68];
    __shared__ float Ka[64][68];
    __shared__ float Kb[64][68];
    const int e = blockIdx.x;
    const int n = blockIdx.y;
    int it = 0, start = 0;
    while (start + it + 1 <= e) { start += it + 1; ++it; }
    const int jt = e - start;
    const int tid = threadIdx.x;
    const float* qh = q + (size_t)n * SEQ * HDIM;
    const float* kh = k + (size_t)n * SEQ * HDIM;

    #pragma unroll
    for (int l = 0; l < 4; ++l) {
        int idx = tid + l * 256;
        int tok = idx >> 4, d4 = (idx & 15) << 2;
        *(float4*)&Qs[tok][d4] = *(const float4*)(qh + (it * 64 + tok) * HDIM + d4);
        *(float4*)&Ka[tok][d4] = *(const float4*)(kh + (it * 64 + tok) * HDIM + d4);
        *(float4*)&Kb[tok][d4] = *(const float4*)(kh + (jt * 64 + tok) * HDIM + d4);
    }
    __syncthreads();

    const int tm = (tid >> 4) << 2;
    const int tn = (tid & 15) << 2;
    float sacc[4][4] = {};
    float gacc[4][4] = {};
    #pragma unroll 4
    for (int d4 = 0; d4 < 16; ++d4) {
        float4 qr[4], ar[4], br[4];
        #pragma unroll
        for (int u = 0; u < 4; ++u) {
            qr[u] = *(const float4*)&Qs[tm + u][d4 << 2];
            ar[u] = *(const float4*)&Ka[tm + u][d4 << 2];
        }
        #pragma unroll
        for (int w2 = 0; w2 < 4; ++w2)
            br[w2] = *(const float4*)&Kb[tn + w2][d4 << 2];
        #pragma unroll
        for (int u = 0; u < 4; ++u)
            #pragma unroll
            for (int w2 = 0; w2 < 4; ++w2) {
                float s = sacc[u][w2];
                s = fmaf(qr[u].x, br[w2].x, s);
                s = fmaf(qr[u].y, br[w2].y, s);
                s = fmaf(qr[u].z, br[w2].z, s);
                s = fmaf(qr[u].w, br[w2].w, s);
                sacc[u][w2] = s;
                float g = gacc[u][w2];
                g = fmaf(ar[u].x, br[w2].x, g);
                g = fmaf(ar[u].y, br[w2].y, g);
                g = fmaf(ar[u].z, br[w2].z, g);
                g = fmaf(ar[u].w, br[w2].w, g);
                gacc[u][w2] = g;
            }
    }
    float* gdst = KKT + ((size_t)n * 36 + e) * 4096;
    #pragma unroll
    for (int u = 0; u < 4; ++u) {
        int i = it * 64 + tm + u;
        float4 o = {sacc[u][0], sacc[u][1], sacc[u][2], sacc[u][3]};
        *(float4*)(S + ((size_t)n * SEQ + i) * SEQ + jt * 64 + tn) = o;
        float4 g = {gacc[u][0], gacc[u][1], gacc[u][2], gacc[u][3]};
        *(float4*)(gdst + (tm + u) * 64 + tn) = g;
    }
}

// hybrid log: exact exponent + hardware f32 log2 of mantissa.
__device__ inline double hybrid_log(double a)
{
    a = fmax(a, 1e-300);
    unsigned long long b = __double_as_longlong(a);
    int e2 = (int)((b >> 52) & 0x7FF) - 1022;
    double m = __longlong_as_double((b & 0x000FFFFFFFFFFFFFULL) |
                                    0x3FE0000000000000ULL);   // [0.5,1)
    return ((double)__log2f((float)m) + (double)e2) * 0.6931471805599453;
}

// sorting-network comparator: descending value, ascending index on tie
#define CSW(a, b)                                                        \
    {                                                                    \
        bool sw = (v##a < v##b) || ((v##a == v##b) && (j##a > j##b));    \
        float tf = sw ? v##b : v##a;                                     \
        float uf = sw ? v##a : v##b;                                     \
        int ti = sw ? j##b : j##a;                                       \
        int ui = sw ? j##a : j##b;                                       \
        v##a = tf; v##b = uf; j##a = ti; j##b = ui;                      \
    }

// ---------------------------------------------------------------
// Kernel 3: per-token DPP. 128-thread blocks = 2 INDEPENDENT waves
// (one token each); all LDS wave-private -> NO __syncthreads at all
// (DS ops retire in order within a wave; lgkmcnt fences at phase
// boundaries). Top-16 via per-lane presorted lists + head-reduce.
// ---------------------------------------------------------------
__global__ __launch_bounds__(128) void dpp_kernel(
    const float* __restrict__ v, float* __restrict__ S,
    const float* __restrict__ KKT, const float* __restrict__ gate_p,
    float* __restrict__ y, float* __restrict__ denomArr)
{
    const int tid  = threadIdx.x;
    const int wid  = tid >> 6;
    const int lane = tid & 63;
    const int i = blockIdx.x * 2 + wid;
    const int n = blockIdx.y;
    const float* vh = v + (size_t)n * SEQ * HDIM;
    const float* KKTh = KKT + (size_t)n * 36 * 4096;
    float* Srow = S + ((size_t)n * SEQ + i) * SEQ;

    __shared__ float prow[2][SEQ];
    __shared__ float gramf[2][17][17];
    __shared__ int   eidx[2][17];

    // ---- load sim row (masked) ----
    float sim8[8];
    #pragma unroll
    for (int m = 0; m < 8; ++m) {
        int j = lane + (m << 6);
        sim8[m] = (j <= i) ? Srow[j] : NEGINF;
    }

    // ---- top-16: presort 8 per lane (19-comparator Batcher network,
    //      stable tie = lower index), then 16 head-reduce rounds ----
    {
        float v0 = sim8[0], v1 = sim8[1], v2 = sim8[2], v3 = sim8[3],
              v4 = sim8[4], v5 = sim8[5], v6 = sim8[6], v7 = sim8[7];
        int j0 = lane, j1 = lane + 64, j2 = lane + 128, j3 = lane + 192,
            j4 = lane + 256, j5 = lane + 320, j6 = lane + 384, j7 = lane + 448;
        CSW(0, 1) CSW(2, 3) CSW(4, 5) CSW(6, 7)
        CSW(0, 2) CSW(1, 3) CSW(4, 6) CSW(5, 7)
        CSW(1, 2) CSW(5, 6)
        CSW(0, 4) CSW(1, 5) CSW(2, 6) CSW(3, 7)
        CSW(2, 4) CSW(3, 5)
        CSW(1, 2) CSW(3, 4) CSW(5, 6)

        if (lane == 0) eidx[wid][0] = i;
        #pragma unroll
        for (int s = 0; s < TOPM; ++s) {
            float rv = v0;
            #pragma unroll
            for (int off = 32; off; off >>= 1)
                rv = fmaxf(rv, __shfl_xor(rv, off));
            unsigned long long tied = __ballot(v0 == rv);
            int ri;
            if (__popcll(tied) == 1) {
                ri = __shfl(j0, (int)__builtin_ctzll(tied));
            } else {
                int cnd = (v0 == rv) ? j0 : 0x7FFFFFFF;
                #pragma unroll
                for (int off = 32; off; off >>= 1)
                    cnd = min(cnd, __shfl_xor(cnd, off));
                ri = cnd;
            }
            if (lane == 0) eidx[wid][1 + s] = ri;
            if (v0 == rv && j0 == ri) {   // unique winner pops its head
                v0 = v1; j0 = j1; v1 = v2; j1 = j2; v2 = v3; j2 = j3;
                v3 = v4; j3 = j4; v4 = v5; j4 = j5; v5 = v6; j5 = j6;
                v6 = v7; j6 = j7; v7 = -3e38f; j7 = 1023;
            }
        }
    }

    // ---- softmax stats; write numerators to LDS + global (P over S) ----
    const float scale = 0.125f;
    float lm = -3e38f;
    #pragma unroll
    for (int m = 0; m < 8; ++m) lm = fmaxf(lm, sim8[m]);
    #pragma unroll
    for (int off = 32; off; off >>= 1) lm = fmaxf(lm, __shfl_xor(lm, off));
    const float mx = lm * scale;
    float sum = 0.f;
    #pragma unroll
    for (int m = 0; m < 8; ++m) {
        float p = expf(sim8[m] * scale - mx);   // 0 for masked entries
        int j = lane + (m << 6);
        prow[wid][j] = p;
        Srow[j] = p;
        sum += p;
    }
    #pragma unroll
    for (int off = 32; off; off >>= 1) sum += __shfl_xor(sum, off);
    const float denom = sum;
    asm volatile("s_waitcnt lgkmcnt(0)" ::: "memory");  // eidx/prow visible

    // ---- 17x17 Gram: gather from precomputed KKT (f32, exact copy) ----
    for (int e = lane; e < 153; e += 64) {
        int a = 0, st = 0;
        while (st + a + 1 <= e) { st += a + 1; ++a; }
        int b = e - st;
        int ra = eidx[wid][a], rb = eidx[wid][b];
        int row = ra > rb ? ra : rb;
        int col = ra > rb ? rb : ra;
        int itt = row >> 6, jtt = col >> 6;
        int p = ((itt * (itt + 1)) >> 1) + jtt;
        float s = KKTh[((size_t)p * 64 + (row & 63)) * 64 + (col & 63)];
        gramf[wid][a][b] = s;
        gramf[wid][b][a] = s;
    }
    asm volatile("s_waitcnt lgkmcnt(0)" ::: "memory");  // gram visible

    // ---- greedy DPP via incremental Cholesky (lazy log: score only
    //      needed from it2>=2; initial cur is provably dead) ----
    int selI[SMAX];
    int sc = 1;
    {
        const int c = lane;
        const bool isCand = (c < TOPM);
        const int nvalid = (i + 1 < TOPM) ? (i + 1) : TOPM;
        bool active = isCand && (c < nvalid) && (eidx[wid][1 + c] != i);
        double zc[7];
        #pragma unroll
        for (int t = 0; t < 7; ++t) zc[t] = 0.0;
        double det = (double)gramf[wid][0][0];
        double cur = 0.0;
        double L00 = sqrt(det > 0.0 ? det : 1e-30);
        double dcv = 0.0;
        if (isCand) {
            zc[0] = (double)gramf[wid][1 + c][0] / L00;
            dcv = (double)gramf[wid][1 + c][1 + c] - zc[0] * zc[0];
        }
        #pragma unroll
        for (int t = 0; t < SMAX; ++t) selI[t] = i;

        for (int it2 = 0; it2 < SMAX - 1; ++it2) {
            double argc = det * dcv + 1e-6;
            // ranking key (monotone in score; arg<=0 == NaN wins argmax)
            double key = active ? (argc > 0.0 ? argc : 1e300) : -1.0;
            int rc = c;
            #pragma unroll
            for (int off = 1; off <= 8; off <<= 1) {
                double ov = __shfl_xor(key, off);
                int    oc = __shfl_xor(rc, off);
                if (ov > key || (ov == key && oc < rc)) { key = ov; rc = oc; }
            }
            rc = __shfl(rc, 0);
            bool any = (__any(active ? 1 : 0) != 0);
            double dbest = __shfl(dcv, rc);
            bool take;
            if (it2 < 2) {
                take = any;                       // sc<4 forces take
            } else {
                double argb = det * dbest + 1e-6;
                bool pos = argb > 0.0;
                double score = hybrid_log(pos ? argb : 1.0) / (double)(sc + 1);
                take = any && (it2 < 3 || (pos && score > cur));
                if (take) cur = pos ? score : __builtin_nan("");
            }
            if (!take) break;

            double Lss = sqrt(dbest > 1e-30 ? dbest : 1e-30);
            double zb[7];
            #pragma unroll
            for (int t = 0; t < 7; ++t) zb[t] = __shfl(zc[t], rc);
            if (isCand) {
                double crossn = (double)gramf[wid][1 + c][1 + rc];
                double s2 = 0.0;
                #pragma unroll
                for (int t = 0; t < 7; ++t) if (t < sc) s2 += zc[t] * zb[t];
                double znew = (crossn - s2) / Lss;
                #pragma unroll
                for (int t = 0; t < 7; ++t) if (t == sc) zc[t] = znew;
                dcv -= znew * znew;
            }
            det = det * dbest;
            if (c == rc) active = false;
            int newIdx = eidx[wid][1 + rc];
            #pragma unroll
            for (int t = 0; t < SMAX; ++t) if (t == sc) selI[t] = newIdx;
            ++sc;
        }
    }

    // ---- gated DPP part -> y (pv_gemm accumulates the std part) ----
    float wsum = 0.f;
    #pragma unroll
    for (int s = 0; s < SMAX; ++s) if (s < sc) wsum += prow[wid][selI[s]];
    float yd = 0.f;
    #pragma unroll
    for (int s = 0; s < SMAX; ++s)
        if (s < sc) yd = fmaf(prow[wid][selI[s]], vh[selI[s] * HDIM + lane], yd);
    const float gp = gate_p[0];
    const float gate = 1.f / (1.f + expf(-gp));
    y[((size_t)n * SEQ + i) * HDIM + lane] = gate * yd / wsum;
    if (lane == 0) denomArr[n * SEQ + i] = denom;
}

// ---------------------------------------------------------------
// Kernel 4: y += (1-gate) * (P @ V)/denom (unchanged from R7).
// ---------------------------------------------------------------
__global__ __launch_bounds__(256) void pv_gemm_kernel(
    const float* __restrict__ P, const float* __restrict__ v,
    const float* __restrict__ denomArr, const float* __restrict__ gate_p,
    float* __restrict__ y)
{
    __shared__ float Ps[64][36];
    __shared__ float Vs[32][68];
    const int tt = blockIdx.x;
    const int n  = blockIdx.y;
    const int t0 = tt * 64;
    const int tid = threadIdx.x;
    const float* Ph = P + (size_t)n * SEQ * SEQ;
    const float* vh = v + (size_t)n * SEQ * HDIM;
    const int tm = (tid >> 4) << 2;
    const int tn = (tid & 15) << 2;
    float acc[4][4] = {};
    const int jmax = t0 + 64;
    for (int j0 = 0; j0 < jmax; j0 += 32) {
        #pragma unroll
        for (int l = 0; l < 2; ++l) {
            int idx = tid + l * 256;
            int tok = idx >> 3, j4 = (idx & 7) << 2;
            *(float4*)&Ps[tok][j4] =
                *(const float4*)(Ph + (t0 + tok) * SEQ + j0 + j4);
        }
        #pragma unroll
        for (int l = 0; l < 2; ++l) {
            int idx = tid + l * 256;
            int j = idx >> 4, d4 = (idx & 15) << 2;
            *(float4*)&Vs[j][d4] = *(const float4*)(vh + (j0 + j) * HDIM + d4);
        }
        __syncthreads();
        #pragma unroll
        for (int j4 = 0; j4 < 8; ++j4) {
            float4 p0r = *(const float4*)&Ps[tm + 0][j4 << 2];
            float4 p1r = *(const float4*)&Ps[tm + 1][j4 << 2];
            float4 p2r = *(const float4*)&Ps[tm + 2][j4 << 2];
            float4 p3r = *(const float4*)&Ps[tm + 3][j4 << 2];
            float pr[4][4] = {{p0r.x, p0r.y, p0r.z, p0r.w},
                              {p1r.x, p1r.y, p1r.z, p1r.w},
                              {p2r.x, p2r.y, p2r.z, p2r.w},
                              {p3r.x, p3r.y, p3r.z, p3r.w}};
            #pragma unroll
            for (int l = 0; l < 4; ++l) {
                float4 v4 = *(const float4*)&Vs[(j4 << 2) + l][tn];
                float vv[4] = {v4.x, v4.y, v4.z, v4.w};
                #pragma unroll
                for (int u = 0; u < 4; ++u)
                    #pragma unroll
                    for (int w2 = 0; w2 < 4; ++w2)
                        acc[u][w2] = fmaf(pr[u][l], vv[w2], acc[u][w2]);
            }
        }
        __syncthreads();
    }
    const float gp = gate_p[0];
    const float gate = 1.f / (1.f + expf(-gp));
    #pragma unroll
    for (int u = 0; u < 4; ++u) {
        int i = t0 + tm + u;
        float den = denomArr[n * SEQ + i];
        #pragma unroll
        for (int w2 = 0; w2 < 4; ++w2) {
            int d = tn + w2;
            size_t off = ((size_t)n * SEQ + i) * HDIM + d;
            y[off] += (1.f - gate) * acc[u][w2] / den;
        }
    }
}

// ---------------------------------------------------------------
// Kernel 5a: proj partial GEMM, K-split x4 (unchanged from R7).
// ---------------------------------------------------------------
__global__ __launch_bounds__(256) void proj_gemm_kernel(
    const float* __restrict__ y, const float* __restrict__ w,
    float* __restrict__ partial)
{
    __shared__ float As[64][36];
    __shared__ float Bs[32][68];
    const int bm = blockIdx.y * 64;
    const int bn = blockIdx.x * 64;
    const int kbase = blockIdx.z * 192;
    const int tid = threadIdx.x;
    const int tm = (tid >> 4) << 2;
    const int tn = (tid & 15) << 2;
    const int alm = tid >> 2;
    const int alk = (tid & 3) << 3;
    const int blk = tid >> 3;
    const int bln = (tid & 7) << 3;
    const int row = bm + alm;
    const int b_ = row >> 9, tk = row & 511;
    const float* ybase = y + (((size_t)b_ * NHEAD) * SEQ + tk) * HDIM;

    float acc[4][4] = {};
    for (int t = 0; t < 6; ++t) {
        const int k0 = kbase + t * 32;
        int col0 = k0 + alk;
        int h0 = col0 >> 6, d0 = col0 & 63;
        float4 a0 = *(const float4*)(ybase + (size_t)h0 * SEQ * HDIM + d0);
        int col1 = col0 + 4;
        int h1 = col1 >> 6, d1 = col1 & 63;
        float4 a1 = *(const float4*)(ybase + (size_t)h1 * SEQ * HDIM + d1);
        float4 b0 = *(const float4*)(w + (k0 + blk) * CDIM + bn + bln);
        float4 b1 = *(const float4*)(w + (k0 + blk) * CDIM + bn + bln + 4);
        *(float4*)&As[alm][alk] = a0;
        *(float4*)&As[alm][alk + 4] = a1;
        *(float4*)&Bs[blk][bln] = b0;
        *(float4*)&Bs[blk][bln + 4] = b1;
        __syncthreads();
        #pragma unroll
        for (int k4 = 0; k4 < 8; ++k4) {
            float4 a0r = *(const float4*)&As[tm + 0][k4 << 2];
            float4 a1r = *(const float4*)&As[tm + 1][k4 << 2];
            float4 a2r = *(const float4*)&As[tm + 2][k4 << 2];
            float4 a3r = *(const float4*)&As[tm + 3][k4 << 2];
            float ar[4][4] = {{a0r.x, a0r.y, a0r.z, a0r.w},
                              {a1r.x, a1r.y, a1r.z, a1r.w},
                              {a2r.x, a2r.y, a2r.z, a2r.w},
                              {a3r.x, a3r.y, a3r.z, a3r.w}};
            #pragma unroll
            for (int j = 0; j < 4; ++j) {
                float4 b4 = *(const float4*)&Bs[(k4 << 2) + j][tn];
                float bb[4] = {b4.x, b4.y, b4.z, b4.w};
                #pragma unroll
                for (int u = 0; u < 4; ++u)
                    #pragma unroll
                    for (int w2 = 0; w2 < 4; ++w2)
                        acc[u][w2] = fmaf(ar[u][j], bb[w2], acc[u][w2]);
            }
        }
        __syncthreads();
    }
    float* dst = partial + (size_t)blockIdx.z * (1024 * 768);
    #pragma unroll
    for (int u = 0; u < 4; ++u) {
        float4 o = {acc[u][0], acc[u][1], acc[u][2], acc[u][3]};
        *(float4*)(dst + (size_t)(bm + tm + u) * 768 + bn + tn) = o;
    }
}

// ---------------------------------------------------------------
// Kernel 5b: proj reduce (unchanged).
// ---------------------------------------------------------------
__global__ __launch_bounds__(256) void proj_reduce_kernel(
    const float* __restrict__ partial, const float* __restrict__ bias,
    float* __restrict__ out)
{
    const int idx = blockIdx.x * 256 + threadIdx.x;   // 0..196607
    const int m = idx / 192;
    const int cc = (idx - m * 192) << 2;
    const size_t MN = (size_t)1024 * 768;
    float4 p0 = *(const float4*)(partial + (size_t)m * 768 + cc);
    float4 p1 = *(const float4*)(partial + MN + (size_t)m * 768 + cc);
    float4 p2 = *(const float4*)(partial + 2 * MN + (size_t)m * 768 + cc);
    float4 p3 = *(const float4*)(partial + 3 * MN + (size_t)m * 768 + cc);
    float4 b4 = *(const float4*)(bias + cc);
    float4 o = {((p0.x + p1.x) + p2.x) + p3.x + b4.x,
                ((p0.y + p1.y) + p2.y) + p3.y + b4.y,
                ((p0.z + p1.z) + p2.z) + p3.z + b4.z,
                ((p0.w + p1.w) + p2.w) + p3.w + b4.w};
    *(float4*)(out + (size_t)m * 768 + cc) = o;
}

extern "C" void kernel_launch(void* const* d_in, const int* in_sizes, int n_in,
                              void* d_out, int out_size, void* d_ws, size_t ws_size,
                              hipStream_t stream)
{
    const float* x      = (const float*)d_in[0];
    const float* w_qkv  = (const float*)d_in[1];
    const float* b_qkv  = (const float*)d_in[2];
    const float* w_proj = (const float*)d_in[3];
    const float* b_proj = (const float*)d_in[4];
    const float* gate_p = (const float*)d_in[5];
    float* out = (float*)d_out;

    float* ws = (float*)d_ws;
    const size_t HS = (size_t)NBATCH * NHEAD * SEQ * HDIM;   // 786432
    const size_t SS = (size_t)NBATCH * NHEAD * SEQ * SEQ;    // 6291456
    float* q   = ws;
    float* k   = q + HS;
    float* v   = k + HS;
    float* y   = v + HS;
    float* S   = y + HS;                 // sim->P in place; also GEMM scratch
    float* den = S + SS;
    float* KKT = den + 16384;            // 24*36*4096 floats, packed tiles

    qkv_gemm_kernel<<<dim3((3 * CDIM) / 64, (NBATCH * SEQ) / 64, 2), 256, 0, stream>>>(
        x, w_qkv, S);
    qkv_reduce_kernel<<<2304, 256, 0, stream>>>(S, b_qkv, q, k, v);
    qkkt_kernel<<<dim3(36, NBATCH * NHEAD), 256, 0, stream>>>(q, k, S, KKT);
    dpp_kernel<<<dim3(SEQ / 2, NBATCH * NHEAD), 128, 0, stream>>>(
        v, S, KKT, gate_p, y, den);
    pv_gemm_kernel<<<dim3(SEQ / 64, NBATCH * NHEAD), 256, 0, stream>>>(
        S, v, den, gate_p, y);
    proj_gemm_kernel<<<dim3(CDIM / 64, (NBATCH * SEQ) / 64, 4), 256, 0, stream>>>(
        y, w_proj, S);
    proj_reduce_kernel<<<768, 256, 0, stream>>>(S, b_proj, out);
}